// Round 12
// baseline (141.006 us; speedup 1.0000x reference)
//
#include <hip/hip_runtime.h>
#include <hip/hip_bf16.h>
#include <math.h>

#define DIM   128
#define NA    256
#define NB    64
#define LPROT 2048
#define KSZ   11

// protein conv tiling (fp8 LDS)
#define TROWS   64
#define NTILES  (LPROT / TROWS)   // 32
#define FRS     152               // fp8 row stride bytes (8 pad + 128 + 16)
#define XRS     136               // bufX bf16 row stride elems (272 B)
#define B0_ROWS 106
#define B1_ROWS 96

typedef __attribute__((ext_vector_type(8))) short short8v;
typedef __attribute__((ext_vector_type(4))) short short4v;
typedef __attribute__((ext_vector_type(4))) float float4v;

__device__ inline unsigned short f2bf(float f) {
  __hip_bfloat16 h = __float2bfloat16(f);
  unsigned short u; __builtin_memcpy(&u, &h, 2); return u;
}
__device__ inline float bf2f(unsigned short s) {
  union { unsigned u; float f; } v; v.u = ((unsigned)s) << 16;
  return v.f;
}
__device__ inline short8v cvt8(const float* p) {
  float4 x = *(const float4*)p, y = *(const float4*)(p + 4);
  short8v t;
  t[0] = (short)f2bf(x.x); t[1] = (short)f2bf(x.y);
  t[2] = (short)f2bf(x.z); t[3] = (short)f2bf(x.w);
  t[4] = (short)f2bf(y.x); t[5] = (short)f2bf(y.y);
  t[6] = (short)f2bf(y.z); t[7] = (short)f2bf(y.w);
  return t;
}

// LDS swizzled addressing (bytes)
#define HSTR 512
#define WSTR 256
__device__ inline int xsa(int n, int cb) { return (n * 256 + cb) ^ ((n & 7) << 4); }
__device__ inline int hta(int e, int nb) { return (e * HSTR + nb) ^ ((e & 7) << 4); }
__device__ inline int wga(int e, int cb) { return (e * WSTR + cb) ^ ((e & 7) << 4); }

// --------- fused preprocessing: A fp32->bf16 + banded fp8 Toeplitz weights --
__global__ __launch_bounds__(256) void k_pre(const float* __restrict__ A,
                                             unsigned short* __restrict__ Abf,
                                             const float* __restrict__ Wc,
                                             long* __restrict__ wbf) {
  int blk = blockIdx.x;
  if (blk < 2048) {
    long i = ((long)blk * 256 + threadIdx.x) * 8;
    *(short8v*)(Abf + i) = cvt8(A + i);
  } else if (threadIdx.x < 192) {
    int t = threadIdx.x;
    int lp = t >> 6, lane = t & 63;
    int lj = lane & 15, k0 = (lane >> 4) * 8;
    int bbase = 15 + k0 - lj;
    for (int ki = 0; ki < KSZ; ++ki) {
      float wr[8];
      #pragma unroll
      for (int i = 0; i < 8; ++i) {
        int t2 = bbase + i - 18;
        wr[i] = (t2 >= 0 && t2 < KSZ) ? Wc[lp * KSZ * KSZ + ki * KSZ + t2] : 0.f;
      }
      int lo = __builtin_amdgcn_cvt_pk_fp8_f32(wr[0], wr[1], 0, false);
      lo = __builtin_amdgcn_cvt_pk_fp8_f32(wr[2], wr[3], lo, true);
      int hi = __builtin_amdgcn_cvt_pk_fp8_f32(wr[4], wr[5], 0, false);
      hi = __builtin_amdgcn_cvt_pk_fp8_f32(wr[6], wr[7], hi, true);
      wbf[(lp * 64 + lane) * KSZ + ki] = ((long)hi << 32) | (unsigned)lo;
    }
  }
}

// ---------------- GNN layer: 256 blocks (4/batch), fully LDS-staged ---------
// Phase 1: stage Wg + ALL 256 xs rows (bf16, swizzled LDS).
// Phase 2: hs = relu(xs@Wg^T+bg) for all 256 rows (4x redundant) -> hsT overlay.
// Phase 3: own 64 rows: xs_out = old + A @ hs  (or masked compound partials).
template <bool GATHER, bool LAST>
__global__ __launch_bounds__(512, 1) void k_layer(
    const float* __restrict__ xs_in,
    const int* __restrict__ fp,
    const float* __restrict__ emb,
    const unsigned short* __restrict__ Abf,
    const float* __restrict__ Wg,
    const float* __restrict__ bg,
    const float* __restrict__ cmask,
    float* __restrict__ xs_out,
    float* __restrict__ cred) {
  __shared__ __align__(16) char pool[98304];
  char* reg0 = pool;          // xs_lds bf16[256][128] -> hsT bf16[128][256] overlay
  char* wgp  = pool + 65536;  // Wg bf16[128][128]

  const int blk = blockIdx.x, b = blk >> 2, q = blk & 3;
  const int tid = threadIdx.x, lane = tid & 63, w = tid >> 6;   // 8 waves
  const int lj = lane & 15, g = lane >> 4, k0 = g * 8;

  // ---- stage Wg as bf16
  for (int i = tid; i < 128 * 16; i += 512) {
    int row = i >> 4, c8 = (i & 15) * 8;
    *(short8v*)(wgp + wga(row, c8 * 2)) = cvt8(&Wg[row * DIM + c8]);
  }
  // ---- stage all 256 xs rows as bf16
  for (int i = tid; i < 256 * 16; i += 512) {
    int r = i >> 4, c8 = (i & 15) * 8;
    const float* src = GATHER ? &emb[(long)fp[b * NA + r] * DIM + c8]
                              : &xs_in[((long)b * NA + r) * DIM + c8];
    *(short8v*)(reg0 + xsa(r, c8 * 2)) = cvt8(src);
  }
  __syncthreads();

  // ---- hs GEMM: wave w computes rows w*32 .. w*32+31 (all 256 across waves)
  const int rbase = w * 32;
  float4v hacc[2][8];
  #pragma unroll
  for (int m = 0; m < 2; ++m)
    #pragma unroll
    for (int c = 0; c < 8; ++c) hacc[m][c] = (float4v){0.f, 0.f, 0.f, 0.f};
  #pragma unroll
  for (int ks = 0; ks < 4; ++ks) {
    short8v a0 = *(const short8v*)(reg0 + xsa(rbase + lj,      ks * 64 + g * 16));
    short8v a1 = *(const short8v*)(reg0 + xsa(rbase + 16 + lj, ks * 64 + g * 16));
    #pragma unroll
    for (int c = 0; c < 8; ++c) {
      short8v bf = *(const short8v*)(wgp + wga(c * 16 + lj, ks * 64 + g * 16));
      hacc[0][c] = __builtin_amdgcn_mfma_f32_16x16x32_bf16(a0, bf, hacc[0][c], 0, 0, 0);
      hacc[1][c] = __builtin_amdgcn_mfma_f32_16x16x32_bf16(a1, bf, hacc[1][c], 0, 0, 0);
    }
  }
  __syncthreads();   // all xs_lds reads done before hsT overlay

  // ---- relu(hacc+bg) -> hsT (transposed, overlays reg0)
  #pragma unroll
  for (int m = 0; m < 2; ++m) {
    int n0 = rbase + m * 16 + g * 4;
    #pragma unroll
    for (int c = 0; c < 8; ++c) {
      int e = c * 16 + lj;
      float bias = bg[e];
      short4v s;
      #pragma unroll
      for (int jj = 0; jj < 4; ++jj)
        s[jj] = (short)f2bf(fmaxf(hacc[m][c][jj] + bias, 0.f));
      *(short4v*)(reg0 + hta(e, n0 * 2)) = s;
    }
  }
  __syncthreads();

  // ---- adj GEMM: own 64 rows (q*64..), wave tile 32 rows x 32 cols
  const int wr = w >> 2, wc = w & 3;
  const int row0 = q * 64 + wr * 32;

  float4v acc[2][2];
  #pragma unroll
  for (int m = 0; m < 2; ++m)
    #pragma unroll
    for (int c = 0; c < 2; ++c) acc[m][c] = (float4v){0.f, 0.f, 0.f, 0.f};

  #pragma unroll 2
  for (int ks = 0; ks < 8; ++ks) {
    short8v af0 = *(const short8v*)
        &Abf[((long)b * NA + row0 + lj) * NA + ks * 32 + k0];
    short8v af1 = *(const short8v*)
        &Abf[((long)b * NA + row0 + 16 + lj) * NA + ks * 32 + k0];
    #pragma unroll
    for (int c = 0; c < 2; ++c) {
      short8v bf = *(const short8v*)(reg0 + hta(wc * 32 + c * 16 + lj, ks * 64 + g * 16));
      acc[0][c] = __builtin_amdgcn_mfma_f32_16x16x32_bf16(af0, bf, acc[0][c], 0, 0, 0);
      acc[1][c] = __builtin_amdgcn_mfma_f32_16x16x32_bf16(af1, bf, acc[1][c], 0, 0, 0);
    }
  }

  if (!LAST) {
    #pragma unroll
    for (int m = 0; m < 2; ++m)
      #pragma unroll
      for (int jj = 0; jj < 4; ++jj) {
        int row = row0 + m * 16 + g * 4 + jj;
        long base = ((long)b * NA + row) * DIM;
        const float* oldsrc;
        long gbase;
        if (GATHER) { gbase = (long)fp[b * NA + row] * DIM; oldsrc = emb; }
        else { gbase = base; oldsrc = xs_in; }
        #pragma unroll
        for (int c = 0; c < 2; ++c) {
          int col = wc * 32 + c * 16 + lj;
          xs_out[base + col] = oldsrc[gbase + col] + acc[m][c][jj];
        }
      }
  } else {
    float p[2] = {0.f, 0.f};
    #pragma unroll
    for (int m = 0; m < 2; ++m)
      #pragma unroll
      for (int jj = 0; jj < 4; ++jj) {
        int row = row0 + m * 16 + g * 4 + jj;
        float cm = cmask[b * NA + row];
        long base = ((long)b * NA + row) * DIM;
        #pragma unroll
        for (int c = 0; c < 2; ++c) {
          int col = wc * 32 + c * 16 + lj;
          float xv = xs_in[base + col] + acc[m][c][jj];
          p[c] = fmaf(xv, cm, p[c]);
        }
      }
    #pragma unroll
    for (int c = 0; c < 2; ++c) {
      p[c] += __shfl_xor(p[c], 16);
      p[c] += __shfl_xor(p[c], 32);
      if (g == 0)
        cred[((long)b * 8 + q * 2 + wr) * DIM + wc * 32 + c * 16 + lj] = p[c];
    }
  }
}

// -------- k_hv: reduce compound partials, compute compound & hv -------------
__global__ __launch_bounds__(128) void k_hv(const float* __restrict__ cred,
                                            const float* __restrict__ cmask,
                                            const float* __restrict__ Wa,
                                            const float* __restrict__ ba,
                                            float* __restrict__ compound,
                                            float* __restrict__ hv) {
  int b = blockIdx.x, e = threadIdx.x;
  __shared__ float comp[DIM];
  __shared__ float redm[DIM];
  float s = 0.f;
  #pragma unroll
  for (int p = 0; p < 8; ++p) s += cred[((long)b * 8 + p) * DIM + e];
  redm[e] = cmask[b * NA + e] + cmask[b * NA + DIM + e];
  __syncthreads();
  for (int st = 64; st > 0; st >>= 1) {
    if (e < st) redm[e] += redm[e + st];
    __syncthreads();
  }
  float c = s / redm[0];
  compound[b * DIM + e] = c;
  comp[e] = c;
  __syncthreads();
  float acc = 0.f;
  for (int d = 0; d < DIM; d += 4) {
    float4 wv = *(const float4*)&Wa[e * DIM + d];
    float4 x  = *(const float4*)&comp[d];
    acc = fmaf(x.x, wv.x, fmaf(x.y, wv.y, fmaf(x.z, wv.z, fmaf(x.w, wv.w, acc))));
  }
  hv[b * DIM + e] = fmaxf(acc + ba[e], 0.f);
}

// ------------------------- fp8 conv epilogue helper -------------------------
template <bool ROWCHK, bool BF16OUT>
__device__ inline void conv_epi(const float4v& acc, int rc,
                                char* __restrict__ dst,
                                unsigned short* __restrict__ dstX,
                                float bias, int dstart, int lane, int cc) {
  const int lj = lane & 15;
  int orow = rc * 16 + (lane >> 4) * 4;
  int ocol = cc * 16 + lj;
  #pragma unroll
  for (int jj = 0; jj < 4; ++jj) {
    float v = fmaxf(acc[jj] + bias, 0.f);
    if constexpr (BF16OUT) {
      dstX[(orow + jj) * XRS + ocol] = f2bf(v);
    } else {
      char sv = 0;
      if (!ROWCHK || (unsigned)(dstart + orow + jj) < LPROT) {
        int p = __builtin_amdgcn_cvt_pk_fp8_f32(v, 0.f, 0, false);
        sv = (char)p;
      }
      dst[(orow + jj) * FRS + 8 + ocol] = sv;
    }
  }
}

// --------------- fp8 conv phase (Toeplitz MFMA, ILP-2 on row tiles) ---------
template <int N_RC, bool ROWCHK, bool BF16OUT>
__device__ inline void conv_fp8(const char* __restrict__ src, char* __restrict__ dst,
                                unsigned short* __restrict__ dstX,
                                const long* bfr, float bias, int dstart,
                                int lane, int cc) {
  const int lj = lane & 15, k0 = (lane >> 4) * 8;
  const int acol = 8 + cc * 16 + k0;
  #pragma unroll 1
  for (int rp = 0; rp < N_RC / 2; ++rp) {
    const int rc0 = rp * 2, rc1 = rc0 + 1;
    float4v acc0 = {0.f, 0.f, 0.f, 0.f};
    float4v acc1 = {0.f, 0.f, 0.f, 0.f};
    #pragma unroll
    for (int ki = 0; ki < KSZ; ++ki) {
      long a0 = *(const long*)(src + (rc0 * 16 + lj + ki) * FRS + acol);
      long a1 = *(const long*)(src + (rc1 * 16 + lj + ki) * FRS + acol);
      acc0 = __builtin_amdgcn_mfma_f32_16x16x32_fp8_fp8(a0, bfr[ki], acc0, 0, 0, 0);
      acc1 = __builtin_amdgcn_mfma_f32_16x16x32_fp8_fp8(a1, bfr[ki], acc1, 0, 0, 0);
    }
    conv_epi<ROWCHK, BF16OUT>(acc0, rc0, dst, dstX, bias, dstart, lane, cc);
    conv_epi<ROWCHK, BF16OUT>(acc1, rc1, dst, dstX, bias, dstart, lane, cc);
  }
  if (N_RC & 1) {
    const int rc = N_RC - 1;
    float4v acc = {0.f, 0.f, 0.f, 0.f};
    #pragma unroll
    for (int ki = 0; ki < KSZ; ++ki) {
      long a = *(const long*)(src + (rc * 16 + lj + ki) * FRS + acol);
      acc = __builtin_amdgcn_mfma_f32_16x16x32_fp8_fp8(a, bfr[ki], acc, 0, 0, 0);
    }
    conv_epi<ROWCHK, BF16OUT>(acc, rc, dst, dstX, bias, dstart, lane, cc);
  }
}

// ------------- fused protein branch (bufX overlays buf1: 38.4KB LDS) --------
__global__ __launch_bounds__(512, 8) void k_protein(const int* __restrict__ words,
                                                    const float* __restrict__ emb_word,
                                                    const long* __restrict__ wbf,
                                                    const float* __restrict__ bc,
                                                    const float* __restrict__ Wa,
                                                    const float* __restrict__ ba,
                                                    const float* __restrict__ hvec,
                                                    const float* __restrict__ pmask,
                                                    float* __restrict__ prot_part) {
  __shared__ __align__(16) char pool[38400];
  char* buf0 = pool;                                     // fp8, 106x152 (16128)
  char* buf1 = pool + 16128;                             // fp8, 96x152 (14592)
  unsigned short* bufX = (unsigned short*)(pool + 16128);// bf16 64x136, OVERLAYS buf1
  float* wpart = (float*)(pool + 33536);                 // 64x8 (2048)
  float* w_l   = (float*)(pool + 35584);                 // 64 (256)
  float* red   = (float*)(pool + 35840);                 // 4x128 (2048)
  float* h_s   = (float*)(pool + 37888);                 // 128 (512)

  const int tile = blockIdx.x, b = blockIdx.y;
  const int r0   = tile * TROWS;
  const int tid  = threadIdx.x;
  const int lane = tid & 63, wave = tid >> 6;       // 8 waves
  const int lj   = lane & 15;
  const int k0   = (lane >> 4) * 8;
  const int cc   = wave;                            // 16-col chunk per wave

  // ---- zero fp8 buffers
  {
    int4 z = {0, 0, 0, 0};
    int4* p0 = (int4*)pool;
    for (int i = tid; i < 30720 / 16; i += 512) p0[i] = z;
  }
  if (tid < DIM) h_s[tid] = hvec[b * DIM + tid];

  // ---- gather input rows r0-15 .. r0+90 as fp8 into buf0
  for (int idx = tid; idx < B0_ROWS * 32; idx += 512) {
    int rloc = idx >> 5, c4 = idx & 31;
    int rg = r0 - 15 + rloc;
    if (rg >= 0 && rg < LPROT) {
      int w = words[b * LPROT + rg];
      float4 v = ((const float4*)(emb_word + (long)w * DIM))[c4];
      int p = __builtin_amdgcn_cvt_pk_fp8_f32(v.x, v.y, 0, false);
      p = __builtin_amdgcn_cvt_pk_fp8_f32(v.z, v.w, p, true);
      *(int*)(buf0 + rloc * FRS + 8 + c4 * 4) = p;
    }
  }

  // ---- 3 conv layers (fp8 Toeplitz MFMA, precomputed weight fragments)
  #pragma unroll 1
  for (int lp = 0; lp < 3; ++lp) {
    __syncthreads();
    long bfr[KSZ];
    const long* wsrc = wbf + (lp * 64 + lane) * KSZ;
    #pragma unroll
    for (int ki = 0; ki < KSZ; ++ki) bfr[ki] = wsrc[ki];
    float bias = bc[lp];

    if (lp == 0)
      conv_fp8<6, true, false>(buf0, buf1, nullptr, bfr, bias, r0 - 10, lane, cc);
    else if (lp == 1)
      conv_fp8<5, true, false>(buf1, buf0, nullptr, bfr, bias, r0 - 5, lane, cc);
    else
      conv_fp8<4, false, true>(buf0, nullptr, bufX, bfr, bias, r0, lane, cc);
  }
  __syncthreads();

  // ---- hs = relu(X @ Wa^T + ba): X = bufX (bf16), in place
  {
    const char* xb = (const char*)bufX;
    float4v acc[4];
    #pragma unroll
    for (int rc = 0; rc < 4; ++rc) acc[rc] = (float4v){0.f, 0.f, 0.f, 0.f};
    #pragma unroll
    for (int ks = 0; ks < 4; ++ks) {
      const float* wrow = Wa + (cc * 16 + lj) * DIM + ks * 32 + k0;
      short8v bf = cvt8(wrow);
      #pragma unroll
      for (int rc = 0; rc < 4; ++rc) {
        short8v a = *(const short8v*)(xb + (rc * 16 + lj) * (XRS * 2) + (ks * 32 + k0) * 2);
        acc[rc] = __builtin_amdgcn_mfma_f32_16x16x32_bf16(a, bf, acc[rc], 0, 0, 0);
      }
    }
    __syncthreads();
    float bav = ba[cc * 16 + lj];
    #pragma unroll
    for (int rc = 0; rc < 4; ++rc) {
      int orow = rc * 16 + (lane >> 4) * 4;
      int ocol = cc * 16 + lj;
      #pragma unroll
      for (int jj = 0; jj < 4; ++jj) {
        float v = fmaxf(acc[rc][jj] + bav, 0.f);
        bufX[(orow + jj) * XRS + ocol] = f2bf(v);
      }
    }
  }
  __syncthreads();

  // ---- attention weights: w_l = tanh(hs[l]·h) * pmask  (vectorized reads)
  {
    int l = tid >> 3, part = tid & 7, d0 = part * 16;
    short8v v0 = *(const short8v*)&bufX[l * XRS + d0];
    short8v v1 = *(const short8v*)&bufX[l * XRS + d0 + 8];
    float4 h0 = *(const float4*)&h_s[d0];
    float4 h1 = *(const float4*)&h_s[d0 + 4];
    float4 h2 = *(const float4*)&h_s[d0 + 8];
    float4 h3 = *(const float4*)&h_s[d0 + 12];
    float s = 0.f;
    s = fmaf(bf2f((unsigned short)v0[0]), h0.x, s);
    s = fmaf(bf2f((unsigned short)v0[1]), h0.y, s);
    s = fmaf(bf2f((unsigned short)v0[2]), h0.z, s);
    s = fmaf(bf2f((unsigned short)v0[3]), h0.w, s);
    s = fmaf(bf2f((unsigned short)v0[4]), h1.x, s);
    s = fmaf(bf2f((unsigned short)v0[5]), h1.y, s);
    s = fmaf(bf2f((unsigned short)v0[6]), h1.z, s);
    s = fmaf(bf2f((unsigned short)v0[7]), h1.w, s);
    s = fmaf(bf2f((unsigned short)v1[0]), h2.x, s);
    s = fmaf(bf2f((unsigned short)v1[1]), h2.y, s);
    s = fmaf(bf2f((unsigned short)v1[2]), h2.z, s);
    s = fmaf(bf2f((unsigned short)v1[3]), h2.w, s);
    s = fmaf(bf2f((unsigned short)v1[4]), h3.x, s);
    s = fmaf(bf2f((unsigned short)v1[5]), h3.y, s);
    s = fmaf(bf2f((unsigned short)v1[6]), h3.z, s);
    s = fmaf(bf2f((unsigned short)v1[7]), h3.w, s);
    wpart[l * 8 + part] = s;
  }
  __syncthreads();
  if (tid < TROWS) {
    float s = 0.f;
    #pragma unroll
    for (int p = 0; p < 8; ++p) s += wpart[tid * 8 + p];
    w_l[tid] = tanhf(s) * pmask[b * LPROT + r0 + tid];
  }
  __syncthreads();

  // ---- partial protein numerator
  {
    int e = tid & 127, g = tid >> 7;
    float s = 0.f;
    #pragma unroll
    for (int j = 0; j < 16; ++j) {
      int l = g * 16 + j;
      s = fmaf(w_l[l], bf2f(bufX[l * XRS + e]), s);
    }
    red[g * DIM + e] = s;
  }
  __syncthreads();
  if (tid < DIM)
    prot_part[((long)b * NTILES + tile) * DIM + tid] =
        red[tid] + red[DIM + tid] + red[2 * DIM + tid] + red[3 * DIM + tid];
}

// ------------------------------------------------ head MLP + affinity per b
__global__ __launch_bounds__(256) void k_head(const float* __restrict__ prot_part,
                                              const float* __restrict__ pmask,
                                              const float* __restrict__ compound,
                                              const float* __restrict__ Wo,
                                              const float* __restrict__ bo,
                                              const float* __restrict__ Wi,
                                              const float* __restrict__ bi,
                                              float* __restrict__ out) {
  int b = blockIdx.x, tid = threadIdx.x;
  __shared__ float cat[2 * DIM];
  __shared__ float redl[256];

  float ps = 0.f;
  for (int l = tid; l < LPROT; l += 256) ps += pmask[b * LPROT + l];
  redl[tid] = ps; __syncthreads();
  for (int st = 128; st > 0; st >>= 1) {
    if (tid < st) redl[tid] += redl[tid + st];
    __syncthreads();
  }
  float pden = redl[0];
  __syncthreads();

  if (tid < DIM) {
    cat[tid] = compound[b * DIM + tid];
    float s = 0.f;
    for (int t = 0; t < NTILES; ++t) s += prot_part[(b * NTILES + t) * DIM + tid];
    cat[DIM + tid] = s / pden;
  }
  __syncthreads();

  for (int j = 0; j < 2; ++j) {
    const float* W = Wo + j * 2 * DIM * 2 * DIM + tid * 2 * DIM;
    float acc = 0.f;
    for (int d = 0; d < 2 * DIM; d += 4) {
      float4 c = *(const float4*)&cat[d];
      float4 w = *(const float4*)&W[d];
      acc = fmaf(c.x, w.x, fmaf(c.y, w.y, fmaf(c.z, w.z, fmaf(c.w, w.w, acc))));
    }
    float v = fmaxf(acc + bo[j * 2 * DIM + tid], 0.f);
    __syncthreads();
    cat[tid] = v;
    __syncthreads();
  }

  float p = cat[tid] * Wi[tid];
  redl[tid] = p; __syncthreads();
  for (int st = 128; st > 0; st >>= 1) {
    if (tid < st) redl[tid] += redl[tid + st];
    __syncthreads();
  }
  if (tid == 0) out[1 + b] = redl[0] + bi[0];
}

// ----------------------------------------------------------------- MSE loss
__global__ void k_loss(const float* __restrict__ label, float* __restrict__ out) {
  int t = threadIdx.x;
  float d = out[1 + t] - label[t];
  float v = d * d;
  #pragma unroll
  for (int s = 32; s > 0; s >>= 1) v += __shfl_down(v, s);
  if (t == 0) out[0] = v * (1.f / 64.f);
}

extern "C" void kernel_launch(void* const* d_in, const int* in_sizes, int n_in,
                              void* d_out, int out_size, void* d_ws, size_t ws_size,
                              hipStream_t stream) {
  const int*   fingerprints = (const int*)d_in[0];
  const float* adjacency    = (const float*)d_in[1];
  const int*   words        = (const int*)d_in[2];
  const float* cmask        = (const float*)d_in[3];
  const float* pmask        = (const float*)d_in[4];
  const float* label        = (const float*)d_in[5];
  const float* emb_fp       = (const float*)d_in[6];
  const float* emb_word     = (const float*)d_in[7];
  const float* Wg           = (const float*)d_in[8];
  const float* bg           = (const float*)d_in[9];
  const float* Wc           = (const float*)d_in[10];
  const float* bc           = (const float*)d_in[11];
  const float* Wa           = (const float*)d_in[12];
  const float* ba           = (const float*)d_in[13];
  const float* Wo           = (const float*)d_in[14];
  const float* bo           = (const float*)d_in[15];
  const float* Wi           = (const float*)d_in[16];
  const float* bi           = (const float*)d_in[17];
  float* out = (float*)d_out;

  unsigned short* Abf = (unsigned short*)d_ws;                 // 8.39 MB
  float* xs1 = (float*)(Abf + (long)NB * NA * NA);             // 8 MB
  float* xs2 = xs1 + (long)NB * NA * DIM;                      // 8 MB
  float* cred = xs2 + (long)NB * NA * DIM;                     // 64*8*128
  float* compound  = cred + NB * 8 * DIM;
  float* hv        = compound + NB * DIM;
  float* prot_part = hv + NB * DIM;                            // 64*32*128
  long*  wbf       = (long*)(prot_part + NB * NTILES * DIM);   // 3*64*11

  k_pre<<<2049, 256, 0, stream>>>(adjacency, Abf, Wc, wbf);

  k_layer<true,  false><<<256, 512, 0, stream>>>(
      nullptr, fingerprints, emb_fp, Abf, Wg, bg, nullptr, xs1, nullptr);
  k_layer<false, false><<<256, 512, 0, stream>>>(
      xs1, nullptr, nullptr, Abf, Wg + DIM * DIM, bg + DIM, nullptr, xs2, nullptr);
  k_layer<false, true><<<256, 512, 0, stream>>>(
      xs2, nullptr, nullptr, Abf, Wg + 2 * DIM * DIM, bg + 2 * DIM,
      cmask, nullptr, cred);
  k_hv<<<NB, 128, 0, stream>>>(cred, cmask, Wa, ba, compound, hv);

  k_protein<<<dim3(NTILES, NB), 512, 0, stream>>>(words, emb_word, wbf, bc, Wa, ba,
                                                  hv, pmask, prot_part);
  k_head<<<NB, 256, 0, stream>>>(prot_part, pmask, compound, Wo, bo, Wi, bi, out);
  k_loss<<<1, 64, 0, stream>>>(label, out);
}

// Round 13
// 140.900 us; speedup vs baseline: 1.0008x; 1.0008x over previous
//
#include <hip/hip_runtime.h>
#include <hip/hip_bf16.h>
#include <math.h>

#define DIM   128
#define NA    256
#define NB    64
#define LPROT 2048
#define KSZ   11

// protein conv tiling (fp8 LDS)
#define TROWS   64
#define NTILES  (LPROT / TROWS)   // 32
#define FRS     152               // fp8 row stride bytes (8 pad + 128 + 16)
#define XRS     136               // bufX bf16 row stride elems (272 B)
#define B0_ROWS 106
#define B1_ROWS 96

typedef __attribute__((ext_vector_type(8))) short short8v;
typedef __attribute__((ext_vector_type(4))) short short4v;
typedef __attribute__((ext_vector_type(4))) float float4v;

__device__ inline unsigned short f2bf(float f) {
  __hip_bfloat16 h = __float2bfloat16(f);
  unsigned short u; __builtin_memcpy(&u, &h, 2); return u;
}
__device__ inline float bf2f(unsigned short s) {
  union { unsigned u; float f; } v; v.u = ((unsigned)s) << 16;
  return v.f;
}
__device__ inline short8v cvt8(const float* p) {
  float4 x = *(const float4*)p, y = *(const float4*)(p + 4);
  short8v t;
  t[0] = (short)f2bf(x.x); t[1] = (short)f2bf(x.y);
  t[2] = (short)f2bf(x.z); t[3] = (short)f2bf(x.w);
  t[4] = (short)f2bf(y.x); t[5] = (short)f2bf(y.y);
  t[6] = (short)f2bf(y.z); t[7] = (short)f2bf(y.w);
  return t;
}

// LDS swizzled addressing (bytes)
#define HSTR 512
#define WSTR 256
__device__ inline int xsa(int n, int cb) { return (n * 256 + cb) ^ ((n & 7) << 4); }
__device__ inline int hta(int e, int nb) { return (e * HSTR + nb) ^ ((e & 7) << 4); }
__device__ inline int wga(int e, int cb) { return (e * WSTR + cb) ^ ((e & 7) << 4); }

// --------- fused preprocessing: A fp32->bf16 + banded fp8 Toeplitz weights --
__global__ __launch_bounds__(256) void k_pre(const float* __restrict__ A,
                                             unsigned short* __restrict__ Abf,
                                             const float* __restrict__ Wc,
                                             long* __restrict__ wbf) {
  int blk = blockIdx.x;
  if (blk < 2048) {
    long i = ((long)blk * 256 + threadIdx.x) * 8;
    *(short8v*)(Abf + i) = cvt8(A + i);
  } else if (threadIdx.x < 192) {
    int t = threadIdx.x;
    int lp = t >> 6, lane = t & 63;
    int lj = lane & 15, k0 = (lane >> 4) * 8;
    int bbase = 15 + k0 - lj;
    for (int ki = 0; ki < KSZ; ++ki) {
      float wr[8];
      #pragma unroll
      for (int i = 0; i < 8; ++i) {
        int t2 = bbase + i - 18;
        wr[i] = (t2 >= 0 && t2 < KSZ) ? Wc[lp * KSZ * KSZ + ki * KSZ + t2] : 0.f;
      }
      int lo = __builtin_amdgcn_cvt_pk_fp8_f32(wr[0], wr[1], 0, false);
      lo = __builtin_amdgcn_cvt_pk_fp8_f32(wr[2], wr[3], lo, true);
      int hi = __builtin_amdgcn_cvt_pk_fp8_f32(wr[4], wr[5], 0, false);
      hi = __builtin_amdgcn_cvt_pk_fp8_f32(wr[6], wr[7], hi, true);
      wbf[(lp * 64 + lane) * KSZ + ki] = ((long)hi << 32) | (unsigned)lo;
    }
  }
}

// -------------------- fused GNN: one block per batch, A-frags hoisted -------
__global__ __launch_bounds__(512) void k_gnn(const int* __restrict__ fp,
                                             const float* __restrict__ emb,
                                             const unsigned short* __restrict__ Abf,
                                             const float* __restrict__ Wg,
                                             const float* __restrict__ bg,
                                             const float* __restrict__ cmask,
                                             const float* __restrict__ Wa,
                                             const float* __restrict__ ba,
                                             float* __restrict__ compound,
                                             float* __restrict__ hv) {
  __shared__ __align__(16) char pool[65536 + 32768 + 4096 + 640];
  char* reg0 = pool;                                  // xs_lds / hsT_lds
  char* wgp  = pool + 65536;                          // Wg bf16
  float* cred = (float*)(pool + 98304);               // 8 x 128
  float* comp = (float*)(pool + 98304 + 4096);        // 128
  float* scsp = (float*)(pool + 98304 + 4096 + 512);  // 1

  const int b = blockIdx.x;
  const int tid = threadIdx.x, lane = tid & 63, w = tid >> 6;  // 8 waves
  const int lj = lane & 15, g = lane >> 4;
  const int k0 = g * 8;
  const int rbase = w * 32;                           // wave owns 32 atom rows

  // ---- prefetch all 16 A-fragments ONCE (layer-invariant), 64 VGPRs
  short8v af[8][2];
  #pragma unroll
  for (int ks = 0; ks < 8; ++ks) {
    af[ks][0] = *(const short8v*)
        &Abf[((long)b * NA + rbase + lj) * NA + ks * 32 + k0];
    af[ks][1] = *(const short8v*)
        &Abf[((long)b * NA + rbase + 16 + lj) * NA + ks * 32 + k0];
  }

  // ---- init xs registers from emb_fp gather (f32, exact)
  float4v xsacc[2][8];
  {
    int frow[2][4];
    #pragma unroll
    for (int m = 0; m < 2; ++m)
      #pragma unroll
      for (int jj = 0; jj < 4; ++jj)
        frow[m][jj] = fp[b * NA + rbase + m * 16 + g * 4 + jj];
    #pragma unroll
    for (int m = 0; m < 2; ++m)
      #pragma unroll
      for (int c = 0; c < 8; ++c)
        #pragma unroll
        for (int jj = 0; jj < 4; ++jj)
          xsacc[m][c][jj] = emb[(long)frow[m][jj] * DIM + c * 16 + lj];
  }

  #pragma unroll 1
  for (int lp = 0; lp < 3; ++lp) {
    __syncthreads();

    const float* Wgl = Wg + lp * DIM * DIM;
    for (int i = tid; i < 128 * 16; i += 512) {
      int row = i >> 4, c8 = (i & 15) * 8;
      *(short8v*)(wgp + wga(row, c8 * 2)) = cvt8(&Wgl[row * DIM + c8]);
    }

    #pragma unroll
    for (int m = 0; m < 2; ++m) {
      #pragma unroll
      for (int jj = 0; jj < 4; ++jj) {
        int r = rbase + m * 16 + g * 4 + jj;
        #pragma unroll
        for (int c = 0; c < 8; ++c)
          *(unsigned short*)(reg0 + xsa(r, (c * 16 + lj) * 2)) =
              f2bf(xsacc[m][c][jj]);
      }
    }
    __syncthreads();

    float4v hacc[2][8];
    #pragma unroll
    for (int m = 0; m < 2; ++m)
      #pragma unroll
      for (int c = 0; c < 8; ++c) hacc[m][c] = (float4v){0.f, 0.f, 0.f, 0.f};
    #pragma unroll
    for (int ks = 0; ks < 4; ++ks) {
      short8v a0 = *(const short8v*)(reg0 + xsa(rbase + lj,      ks * 64 + g * 16));
      short8v a1 = *(const short8v*)(reg0 + xsa(rbase + 16 + lj, ks * 64 + g * 16));
      #pragma unroll
      for (int c = 0; c < 8; ++c) {
        short8v bf = *(const short8v*)(wgp + wga(c * 16 + lj, ks * 64 + g * 16));
        hacc[0][c] = __builtin_amdgcn_mfma_f32_16x16x32_bf16(a0, bf, hacc[0][c], 0, 0, 0);
        hacc[1][c] = __builtin_amdgcn_mfma_f32_16x16x32_bf16(a1, bf, hacc[1][c], 0, 0, 0);
      }
    }
    __syncthreads();

    #pragma unroll
    for (int m = 0; m < 2; ++m) {
      int n0 = rbase + m * 16 + g * 4;
      #pragma unroll
      for (int c = 0; c < 8; ++c) {
        int e = c * 16 + lj;
        float bias = bg[lp * DIM + e];
        short4v s;
        #pragma unroll
        for (int jj = 0; jj < 4; ++jj)
          s[jj] = (short)f2bf(fmaxf(hacc[m][c][jj] + bias, 0.f));
        *(short4v*)(reg0 + hta(e, n0 * 2)) = s;
      }
    }
    __syncthreads();

    // adj GEMM: xsacc += A @ hs  (A-fragments already in registers)
    #pragma unroll 2
    for (int ks = 0; ks < 8; ++ks) {
      #pragma unroll
      for (int c = 0; c < 8; ++c) {
        short8v bf = *(const short8v*)(reg0 + hta(c * 16 + lj, ks * 64 + g * 16));
        xsacc[0][c] = __builtin_amdgcn_mfma_f32_16x16x32_bf16(af[ks][0], bf, xsacc[0][c], 0, 0, 0);
        xsacc[1][c] = __builtin_amdgcn_mfma_f32_16x16x32_bf16(af[ks][1], bf, xsacc[1][c], 0, 0, 0);
      }
    }
  }
  __syncthreads();

  // ---- compound mean (masked) from xs registers
  {
    float cm[2][4];
    #pragma unroll
    for (int m = 0; m < 2; ++m)
      #pragma unroll
      for (int jj = 0; jj < 4; ++jj)
        cm[m][jj] = cmask[b * NA + rbase + m * 16 + g * 4 + jj];
    #pragma unroll
    for (int c = 0; c < 8; ++c) {
      float p = 0.f;
      #pragma unroll
      for (int m = 0; m < 2; ++m)
        #pragma unroll
        for (int jj = 0; jj < 4; ++jj)
          p = fmaf(xsacc[m][c][jj], cm[m][jj], p);
      p += __shfl_xor(p, 16);
      p += __shfl_xor(p, 32);
      if (g == 0) cred[w * DIM + c * 16 + lj] = p;
    }
    if (w == 0) {
      float s = 0.f;
      for (int i = lane; i < NA; i += 64) s += cmask[b * NA + i];
      #pragma unroll
      for (int o = 32; o > 0; o >>= 1) s += __shfl_xor(s, o);
      if (lane == 0) scsp[0] = s;
    }
  }
  __syncthreads();
  if (tid < DIM) {
    float s = 0.f;
    #pragma unroll
    for (int ww = 0; ww < 8; ++ww) s += cred[ww * DIM + tid];
    float c = s / scsp[0];
    compound[b * DIM + tid] = c;
    comp[tid] = c;
  }
  __syncthreads();
  if (tid < DIM) {
    float acc = 0.f;
    for (int d = 0; d < DIM; d += 4) {
      float4 wv = *(const float4*)&Wa[tid * DIM + d];
      float4 x  = *(const float4*)&comp[d];
      acc = fmaf(x.x, wv.x, fmaf(x.y, wv.y, fmaf(x.z, wv.z, fmaf(x.w, wv.w, acc))));
    }
    hv[b * DIM + tid] = fmaxf(acc + ba[tid], 0.f);
  }
}

// ------------------------- fp8 conv epilogue helper -------------------------
template <bool ROWCHK, bool BF16OUT>
__device__ inline void conv_epi(const float4v& acc, int rc,
                                char* __restrict__ dst,
                                unsigned short* __restrict__ dstX,
                                float bias, int dstart, int lane, int cc) {
  const int lj = lane & 15;
  int orow = rc * 16 + (lane >> 4) * 4;
  int ocol = cc * 16 + lj;
  #pragma unroll
  for (int jj = 0; jj < 4; ++jj) {
    float v = fmaxf(acc[jj] + bias, 0.f);
    if constexpr (BF16OUT) {
      dstX[(orow + jj) * XRS + ocol] = f2bf(v);
    } else {
      char sv = 0;
      if (!ROWCHK || (unsigned)(dstart + orow + jj) < LPROT) {
        int p = __builtin_amdgcn_cvt_pk_fp8_f32(v, 0.f, 0, false);
        sv = (char)p;
      }
      dst[(orow + jj) * FRS + 8 + ocol] = sv;
    }
  }
}

// --------------- fp8 conv phase (Toeplitz MFMA, ILP-2 on row tiles) ---------
template <int N_RC, bool ROWCHK, bool BF16OUT>
__device__ inline void conv_fp8(const char* __restrict__ src, char* __restrict__ dst,
                                unsigned short* __restrict__ dstX,
                                const long* bfr, float bias, int dstart,
                                int lane, int cc) {
  const int lj = lane & 15, k0 = (lane >> 4) * 8;
  const int acol = 8 + cc * 16 + k0;
  #pragma unroll 1
  for (int rp = 0; rp < N_RC / 2; ++rp) {
    const int rc0 = rp * 2, rc1 = rc0 + 1;
    float4v acc0 = {0.f, 0.f, 0.f, 0.f};
    float4v acc1 = {0.f, 0.f, 0.f, 0.f};
    #pragma unroll
    for (int ki = 0; ki < KSZ; ++ki) {
      long a0 = *(const long*)(src + (rc0 * 16 + lj + ki) * FRS + acol);
      long a1 = *(const long*)(src + (rc1 * 16 + lj + ki) * FRS + acol);
      acc0 = __builtin_amdgcn_mfma_f32_16x16x32_fp8_fp8(a0, bfr[ki], acc0, 0, 0, 0);
      acc1 = __builtin_amdgcn_mfma_f32_16x16x32_fp8_fp8(a1, bfr[ki], acc1, 0, 0, 0);
    }
    conv_epi<ROWCHK, BF16OUT>(acc0, rc0, dst, dstX, bias, dstart, lane, cc);
    conv_epi<ROWCHK, BF16OUT>(acc1, rc1, dst, dstX, bias, dstart, lane, cc);
  }
  if (N_RC & 1) {
    const int rc = N_RC - 1;
    float4v acc = {0.f, 0.f, 0.f, 0.f};
    #pragma unroll
    for (int ki = 0; ki < KSZ; ++ki) {
      long a = *(const long*)(src + (rc * 16 + lj + ki) * FRS + acol);
      acc = __builtin_amdgcn_mfma_f32_16x16x32_fp8_fp8(a, bfr[ki], acc, 0, 0, 0);
    }
    conv_epi<ROWCHK, BF16OUT>(acc, rc, dst, dstX, bias, dstart, lane, cc);
  }
}

// ------------- fused protein branch (bufX overlays buf1: 38.4KB LDS) --------
__global__ __launch_bounds__(512, 8) void k_protein(const int* __restrict__ words,
                                                    const float* __restrict__ emb_word,
                                                    const long* __restrict__ wbf,
                                                    const float* __restrict__ bc,
                                                    const float* __restrict__ Wa,
                                                    const float* __restrict__ ba,
                                                    const float* __restrict__ hvec,
                                                    const float* __restrict__ pmask,
                                                    float* __restrict__ prot_part) {
  __shared__ __align__(16) char pool[38400];
  char* buf0 = pool;                                     // fp8, 106x152 (16128)
  char* buf1 = pool + 16128;                             // fp8, 96x152 (14592)
  unsigned short* bufX = (unsigned short*)(pool + 16128);// bf16 64x136, OVERLAYS buf1
  float* wpart = (float*)(pool + 33536);                 // 64x8 (2048)
  float* w_l   = (float*)(pool + 35584);                 // 64 (256)
  float* red   = (float*)(pool + 35840);                 // 4x128 (2048)
  float* h_s   = (float*)(pool + 37888);                 // 128 (512)

  const int tile = blockIdx.x, b = blockIdx.y;
  const int r0   = tile * TROWS;
  const int tid  = threadIdx.x;
  const int lane = tid & 63, wave = tid >> 6;       // 8 waves
  const int lj   = lane & 15;
  const int k0   = (lane >> 4) * 8;
  const int cc   = wave;                            // 16-col chunk per wave

  // ---- zero fp8 buffers
  {
    int4 z = {0, 0, 0, 0};
    int4* p0 = (int4*)pool;
    for (int i = tid; i < 30720 / 16; i += 512) p0[i] = z;
  }
  if (tid < DIM) h_s[tid] = hvec[b * DIM + tid];

  // ---- gather input rows r0-15 .. r0+90 as fp8 into buf0
  for (int idx = tid; idx < B0_ROWS * 32; idx += 512) {
    int rloc = idx >> 5, c4 = idx & 31;
    int rg = r0 - 15 + rloc;
    if (rg >= 0 && rg < LPROT) {
      int w = words[b * LPROT + rg];
      float4 v = ((const float4*)(emb_word + (long)w * DIM))[c4];
      int p = __builtin_amdgcn_cvt_pk_fp8_f32(v.x, v.y, 0, false);
      p = __builtin_amdgcn_cvt_pk_fp8_f32(v.z, v.w, p, true);
      *(int*)(buf0 + rloc * FRS + 8 + c4 * 4) = p;
    }
  }

  // ---- 3 conv layers (fp8 Toeplitz MFMA, precomputed weight fragments)
  #pragma unroll 1
  for (int lp = 0; lp < 3; ++lp) {
    __syncthreads();
    long bfr[KSZ];
    const long* wsrc = wbf + (lp * 64 + lane) * KSZ;
    #pragma unroll
    for (int ki = 0; ki < KSZ; ++ki) bfr[ki] = wsrc[ki];
    float bias = bc[lp];

    if (lp == 0)
      conv_fp8<6, true, false>(buf0, buf1, nullptr, bfr, bias, r0 - 10, lane, cc);
    else if (lp == 1)
      conv_fp8<5, true, false>(buf1, buf0, nullptr, bfr, bias, r0 - 5, lane, cc);
    else
      conv_fp8<4, false, true>(buf0, nullptr, bufX, bfr, bias, r0, lane, cc);
  }
  __syncthreads();

  // ---- hs = relu(X @ Wa^T + ba): X = bufX (bf16), in place
  {
    const char* xb = (const char*)bufX;
    float4v acc[4];
    #pragma unroll
    for (int rc = 0; rc < 4; ++rc) acc[rc] = (float4v){0.f, 0.f, 0.f, 0.f};
    #pragma unroll
    for (int ks = 0; ks < 4; ++ks) {
      const float* wrow = Wa + (cc * 16 + lj) * DIM + ks * 32 + k0;
      short8v bf = cvt8(wrow);
      #pragma unroll
      for (int rc = 0; rc < 4; ++rc) {
        short8v a = *(const short8v*)(xb + (rc * 16 + lj) * (XRS * 2) + (ks * 32 + k0) * 2);
        acc[rc] = __builtin_amdgcn_mfma_f32_16x16x32_bf16(a, bf, acc[rc], 0, 0, 0);
      }
    }
    __syncthreads();
    float bav = ba[cc * 16 + lj];
    #pragma unroll
    for (int rc = 0; rc < 4; ++rc) {
      int orow = rc * 16 + (lane >> 4) * 4;
      int ocol = cc * 16 + lj;
      #pragma unroll
      for (int jj = 0; jj < 4; ++jj) {
        float v = fmaxf(acc[rc][jj] + bav, 0.f);
        bufX[(orow + jj) * XRS + ocol] = f2bf(v);
      }
    }
  }
  __syncthreads();

  // ---- attention weights: w_l = tanh(hs[l]·h) * pmask  (vectorized reads)
  {
    int l = tid >> 3, part = tid & 7, d0 = part * 16;
    short8v v0 = *(const short8v*)&bufX[l * XRS + d0];
    short8v v1 = *(const short8v*)&bufX[l * XRS + d0 + 8];
    float4 h0 = *(const float4*)&h_s[d0];
    float4 h1 = *(const float4*)&h_s[d0 + 4];
    float4 h2 = *(const float4*)&h_s[d0 + 8];
    float4 h3 = *(const float4*)&h_s[d0 + 12];
    float s = 0.f;
    s = fmaf(bf2f((unsigned short)v0[0]), h0.x, s);
    s = fmaf(bf2f((unsigned short)v0[1]), h0.y, s);
    s = fmaf(bf2f((unsigned short)v0[2]), h0.z, s);
    s = fmaf(bf2f((unsigned short)v0[3]), h0.w, s);
    s = fmaf(bf2f((unsigned short)v0[4]), h1.x, s);
    s = fmaf(bf2f((unsigned short)v0[5]), h1.y, s);
    s = fmaf(bf2f((unsigned short)v0[6]), h1.z, s);
    s = fmaf(bf2f((unsigned short)v0[7]), h1.w, s);
    s = fmaf(bf2f((unsigned short)v1[0]), h2.x, s);
    s = fmaf(bf2f((unsigned short)v1[1]), h2.y, s);
    s = fmaf(bf2f((unsigned short)v1[2]), h2.z, s);
    s = fmaf(bf2f((unsigned short)v1[3]), h2.w, s);
    s = fmaf(bf2f((unsigned short)v1[4]), h3.x, s);
    s = fmaf(bf2f((unsigned short)v1[5]), h3.y, s);
    s = fmaf(bf2f((unsigned short)v1[6]), h3.z, s);
    s = fmaf(bf2f((unsigned short)v1[7]), h3.w, s);
    wpart[l * 8 + part] = s;
  }
  __syncthreads();
  if (tid < TROWS) {
    float s = 0.f;
    #pragma unroll
    for (int p = 0; p < 8; ++p) s += wpart[tid * 8 + p];
    w_l[tid] = tanhf(s) * pmask[b * LPROT + r0 + tid];
  }
  __syncthreads();

  // ---- partial protein numerator
  {
    int e = tid & 127, g = tid >> 7;
    float s = 0.f;
    #pragma unroll
    for (int j = 0; j < 16; ++j) {
      int l = g * 16 + j;
      s = fmaf(w_l[l], bf2f(bufX[l * XRS + e]), s);
    }
    red[g * DIM + e] = s;
  }
  __syncthreads();
  if (tid < DIM)
    prot_part[((long)b * NTILES + tile) * DIM + tid] =
        red[tid] + red[DIM + tid] + red[2 * DIM + tid] + red[3 * DIM + tid];
}

// ------------------------------------------------ head MLP + affinity per b
__global__ __launch_bounds__(256) void k_head(const float* __restrict__ prot_part,
                                              const float* __restrict__ pmask,
                                              const float* __restrict__ compound,
                                              const float* __restrict__ Wo,
                                              const float* __restrict__ bo,
                                              const float* __restrict__ Wi,
                                              const float* __restrict__ bi,
                                              float* __restrict__ out) {
  int b = blockIdx.x, tid = threadIdx.x;
  __shared__ float cat[2 * DIM];
  __shared__ float redl[256];

  float ps = 0.f;
  for (int l = tid; l < LPROT; l += 256) ps += pmask[b * LPROT + l];
  redl[tid] = ps; __syncthreads();
  for (int st = 128; st > 0; st >>= 1) {
    if (tid < st) redl[tid] += redl[tid + st];
    __syncthreads();
  }
  float pden = redl[0];
  __syncthreads();

  if (tid < DIM) {
    cat[tid] = compound[b * DIM + tid];
    float s = 0.f;
    for (int t = 0; t < NTILES; ++t) s += prot_part[(b * NTILES + t) * DIM + tid];
    cat[DIM + tid] = s / pden;
  }
  __syncthreads();

  for (int j = 0; j < 2; ++j) {
    const float* W = Wo + j * 2 * DIM * 2 * DIM + tid * 2 * DIM;
    float acc = 0.f;
    for (int d = 0; d < 2 * DIM; d += 4) {
      float4 c = *(const float4*)&cat[d];
      float4 w = *(const float4*)&W[d];
      acc = fmaf(c.x, w.x, fmaf(c.y, w.y, fmaf(c.z, w.z, fmaf(c.w, w.w, acc))));
    }
    float v = fmaxf(acc + bo[j * 2 * DIM + tid], 0.f);
    __syncthreads();
    cat[tid] = v;
    __syncthreads();
  }

  float p = cat[tid] * Wi[tid];
  redl[tid] = p; __syncthreads();
  for (int st = 128; st > 0; st >>= 1) {
    if (tid < st) redl[tid] += redl[tid + st];
    __syncthreads();
  }
  if (tid == 0) out[1 + b] = redl[0] + bi[0];
}

// ----------------------------------------------------------------- MSE loss
__global__ void k_loss(const float* __restrict__ label, float* __restrict__ out) {
  int t = threadIdx.x;
  float d = out[1 + t] - label[t];
  float v = d * d;
  #pragma unroll
  for (int s = 32; s > 0; s >>= 1) v += __shfl_down(v, s);
  if (t == 0) out[0] = v * (1.f / 64.f);
}

extern "C" void kernel_launch(void* const* d_in, const int* in_sizes, int n_in,
                              void* d_out, int out_size, void* d_ws, size_t ws_size,
                              hipStream_t stream) {
  const int*   fingerprints = (const int*)d_in[0];
  const float* adjacency    = (const float*)d_in[1];
  const int*   words        = (const int*)d_in[2];
  const float* cmask        = (const float*)d_in[3];
  const float* pmask        = (const float*)d_in[4];
  const float* label        = (const float*)d_in[5];
  const float* emb_fp       = (const float*)d_in[6];
  const float* emb_word     = (const float*)d_in[7];
  const float* Wg           = (const float*)d_in[8];
  const float* bg           = (const float*)d_in[9];
  const float* Wc           = (const float*)d_in[10];
  const float* bc           = (const float*)d_in[11];
  const float* Wa           = (const float*)d_in[12];
  const float* ba           = (const float*)d_in[13];
  const float* Wo           = (const float*)d_in[14];
  const float* bo           = (const float*)d_in[15];
  const float* Wi           = (const float*)d_in[16];
  const float* bi           = (const float*)d_in[17];
  float* out = (float*)d_out;

  unsigned short* Abf = (unsigned short*)d_ws;                 // 8.39 MB
  float* compound  = (float*)(Abf + (long)NB * NA * NA);
  float* hv        = compound + NB * DIM;
  float* prot_part = hv + NB * DIM;                            // 64*32*128
  long*  wbf       = (long*)(prot_part + NB * NTILES * DIM);   // 3*64*11

  k_pre<<<2049, 256, 0, stream>>>(adjacency, Abf, Wc, wbf);
  k_gnn<<<NB, 512, 0, stream>>>(fingerprints, emb_fp, Abf, Wg, bg,
                                cmask, Wa, ba, compound, hv);
  k_protein<<<dim3(NTILES, NB), 512, 0, stream>>>(words, emb_word, wbf, bc, Wa, ba,
                                                  hv, pmask, prot_part);
  k_head<<<NB, 256, 0, stream>>>(prot_part, pmask, compound, Wo, bo, Wi, bi, out);
  k_loss<<<1, 64, 0, stream>>>(label, out);
}

// Round 14
// 134.974 us; speedup vs baseline: 1.0447x; 1.0439x over previous
//
#include <hip/hip_runtime.h>
#include <hip/hip_bf16.h>
#include <math.h>

#define DIM   128
#define NA    256
#define NB    64
#define LPROT 2048
#define KSZ   11

// protein conv tiling (fp8 LDS)
#define TROWS   64
#define NTILES  (LPROT / TROWS)   // 32
#define FRS     152               // fp8 row stride bytes (8 pad + 128 + 16)
#define XRS     136               // bufX bf16 row stride elems (272 B)
#define B0_ROWS 106
#define B1_ROWS 96

typedef __attribute__((ext_vector_type(8))) short short8v;
typedef __attribute__((ext_vector_type(4))) short short4v;
typedef __attribute__((ext_vector_type(4))) float float4v;

__device__ inline unsigned short f2bf(float f) {
  __hip_bfloat16 h = __float2bfloat16(f);
  unsigned short u; __builtin_memcpy(&u, &h, 2); return u;
}
__device__ inline float bf2f(unsigned short s) {
  union { unsigned u; float f; } v; v.u = ((unsigned)s) << 16;
  return v.f;
}
__device__ inline short8v cvt8(const float* p) {
  float4 x = *(const float4*)p, y = *(const float4*)(p + 4);
  short8v t;
  t[0] = (short)f2bf(x.x); t[1] = (short)f2bf(x.y);
  t[2] = (short)f2bf(x.z); t[3] = (short)f2bf(x.w);
  t[4] = (short)f2bf(y.x); t[5] = (short)f2bf(y.y);
  t[6] = (short)f2bf(y.z); t[7] = (short)f2bf(y.w);
  return t;
}

// LDS swizzled addressing (bytes)
#define HSTR 512
#define WSTR 256
__device__ inline int xsa(int n, int cb) { return (n * 256 + cb) ^ ((n & 7) << 4); }
__device__ inline int hta(int e, int nb) { return (e * HSTR + nb) ^ ((e & 7) << 4); }
__device__ inline int wga(int e, int cb) { return (e * WSTR + cb) ^ ((e & 7) << 4); }

// --------- fused preprocessing: A fp32->bf16 + banded fp8 Toeplitz weights --
__global__ __launch_bounds__(256) void k_pre(const float* __restrict__ A,
                                             unsigned short* __restrict__ Abf,
                                             const float* __restrict__ Wc,
                                             long* __restrict__ wbf) {
  int blk = blockIdx.x;
  if (blk < 2048) {
    long i = ((long)blk * 256 + threadIdx.x) * 8;
    *(short8v*)(Abf + i) = cvt8(A + i);
  } else if (threadIdx.x < 192) {
    int t = threadIdx.x;
    int lp = t >> 6, lane = t & 63;
    int lj = lane & 15, k0 = (lane >> 4) * 8;
    int bbase = 15 + k0 - lj;
    for (int ki = 0; ki < KSZ; ++ki) {
      float wr[8];
      #pragma unroll
      for (int i = 0; i < 8; ++i) {
        int t2 = bbase + i - 18;
        wr[i] = (t2 >= 0 && t2 < KSZ) ? Wc[lp * KSZ * KSZ + ki * KSZ + t2] : 0.f;
      }
      int lo = __builtin_amdgcn_cvt_pk_fp8_f32(wr[0], wr[1], 0, false);
      lo = __builtin_amdgcn_cvt_pk_fp8_f32(wr[2], wr[3], lo, true);
      int hi = __builtin_amdgcn_cvt_pk_fp8_f32(wr[4], wr[5], 0, false);
      hi = __builtin_amdgcn_cvt_pk_fp8_f32(wr[6], wr[7], hi, true);
      wbf[(lp * 64 + lane) * KSZ + ki] = ((long)hi << 32) | (unsigned)lo;
    }
  }
}

// -------------------- fused GNN (r11-validated): one block per batch --------
// A-fragments loaded IN-LOOP (hoisting spills at the 128-VGPR cap; r8/r13).
__global__ __launch_bounds__(512, 2) void k_gnn(const int* __restrict__ fp,
                                                const float* __restrict__ emb,
                                                const unsigned short* __restrict__ Abf,
                                                const float* __restrict__ Wg,
                                                const float* __restrict__ bg,
                                                const float* __restrict__ cmask,
                                                const float* __restrict__ Wa,
                                                const float* __restrict__ ba,
                                                float* __restrict__ compound,
                                                float* __restrict__ hv) {
  __shared__ __align__(16) char pool[65536 + 32768 + 4096 + 640];
  char* reg0 = pool;                                  // xs_lds / hsT_lds
  char* wgp  = pool + 65536;                          // Wg bf16
  float* cred = (float*)(pool + 98304);               // 8 x 128
  float* comp = (float*)(pool + 98304 + 4096);        // 128
  float* scsp = (float*)(pool + 98304 + 4096 + 512);  // 1

  const int b = blockIdx.x;
  const int tid = threadIdx.x, lane = tid & 63, w = tid >> 6;  // 8 waves
  const int lj = lane & 15, g = lane >> 4;
  const int k0 = g * 8;
  const int rbase = w * 32;                           // wave owns 32 atom rows

  float4v xsacc[2][8];
  {
    int frow[2][4];
    #pragma unroll
    for (int m = 0; m < 2; ++m)
      #pragma unroll
      for (int jj = 0; jj < 4; ++jj)
        frow[m][jj] = fp[b * NA + rbase + m * 16 + g * 4 + jj];
    #pragma unroll
    for (int m = 0; m < 2; ++m)
      #pragma unroll
      for (int c = 0; c < 8; ++c)
        #pragma unroll
        for (int jj = 0; jj < 4; ++jj)
          xsacc[m][c][jj] = emb[(long)frow[m][jj] * DIM + c * 16 + lj];
  }

  #pragma unroll 1
  for (int lp = 0; lp < 3; ++lp) {
    __syncthreads();

    const float* Wgl = Wg + lp * DIM * DIM;
    for (int i = tid; i < 128 * 16; i += 512) {
      int row = i >> 4, c8 = (i & 15) * 8;
      *(short8v*)(wgp + wga(row, c8 * 2)) = cvt8(&Wgl[row * DIM + c8]);
    }

    #pragma unroll
    for (int m = 0; m < 2; ++m) {
      #pragma unroll
      for (int jj = 0; jj < 4; ++jj) {
        int r = rbase + m * 16 + g * 4 + jj;
        #pragma unroll
        for (int c = 0; c < 8; ++c)
          *(unsigned short*)(reg0 + xsa(r, (c * 16 + lj) * 2)) =
              f2bf(xsacc[m][c][jj]);
      }
    }
    __syncthreads();

    float4v hacc[2][8];
    #pragma unroll
    for (int m = 0; m < 2; ++m)
      #pragma unroll
      for (int c = 0; c < 8; ++c) hacc[m][c] = (float4v){0.f, 0.f, 0.f, 0.f};
    #pragma unroll
    for (int ks = 0; ks < 4; ++ks) {
      short8v a0 = *(const short8v*)(reg0 + xsa(rbase + lj,      ks * 64 + g * 16));
      short8v a1 = *(const short8v*)(reg0 + xsa(rbase + 16 + lj, ks * 64 + g * 16));
      #pragma unroll
      for (int c = 0; c < 8; ++c) {
        short8v bf = *(const short8v*)(wgp + wga(c * 16 + lj, ks * 64 + g * 16));
        hacc[0][c] = __builtin_amdgcn_mfma_f32_16x16x32_bf16(a0, bf, hacc[0][c], 0, 0, 0);
        hacc[1][c] = __builtin_amdgcn_mfma_f32_16x16x32_bf16(a1, bf, hacc[1][c], 0, 0, 0);
      }
    }
    __syncthreads();

    #pragma unroll
    for (int m = 0; m < 2; ++m) {
      int n0 = rbase + m * 16 + g * 4;
      #pragma unroll
      for (int c = 0; c < 8; ++c) {
        int e = c * 16 + lj;
        float bias = bg[lp * DIM + e];
        short4v s;
        #pragma unroll
        for (int jj = 0; jj < 4; ++jj)
          s[jj] = (short)f2bf(fmaxf(hacc[m][c][jj] + bias, 0.f));
        *(short4v*)(reg0 + hta(e, n0 * 2)) = s;
      }
    }
    __syncthreads();

    // adj GEMM: xsacc += A @ hs  (A bf16, loaded in-loop)
    #pragma unroll 2
    for (int ks = 0; ks < 8; ++ks) {
      short8v af0 = *(const short8v*)
          &Abf[((long)b * NA + rbase + lj) * NA + ks * 32 + k0];
      short8v af1 = *(const short8v*)
          &Abf[((long)b * NA + rbase + 16 + lj) * NA + ks * 32 + k0];
      #pragma unroll
      for (int c = 0; c < 8; ++c) {
        short8v bf = *(const short8v*)(reg0 + hta(c * 16 + lj, ks * 64 + g * 16));
        xsacc[0][c] = __builtin_amdgcn_mfma_f32_16x16x32_bf16(af0, bf, xsacc[0][c], 0, 0, 0);
        xsacc[1][c] = __builtin_amdgcn_mfma_f32_16x16x32_bf16(af1, bf, xsacc[1][c], 0, 0, 0);
      }
    }
  }
  __syncthreads();

  // ---- compound mean (masked) from xs registers
  {
    float cm[2][4];
    #pragma unroll
    for (int m = 0; m < 2; ++m)
      #pragma unroll
      for (int jj = 0; jj < 4; ++jj)
        cm[m][jj] = cmask[b * NA + rbase + m * 16 + g * 4 + jj];
    #pragma unroll
    for (int c = 0; c < 8; ++c) {
      float p = 0.f;
      #pragma unroll
      for (int m = 0; m < 2; ++m)
        #pragma unroll
        for (int jj = 0; jj < 4; ++jj)
          p = fmaf(xsacc[m][c][jj], cm[m][jj], p);
      p += __shfl_xor(p, 16);
      p += __shfl_xor(p, 32);
      if (g == 0) cred[w * DIM + c * 16 + lj] = p;
    }
    if (w == 0) {
      float s = 0.f;
      for (int i = lane; i < NA; i += 64) s += cmask[b * NA + i];
      #pragma unroll
      for (int o = 32; o > 0; o >>= 1) s += __shfl_xor(s, o);
      if (lane == 0) scsp[0] = s;
    }
  }
  __syncthreads();
  if (tid < DIM) {
    float s = 0.f;
    #pragma unroll
    for (int ww = 0; ww < 8; ++ww) s += cred[ww * DIM + tid];
    float c = s / scsp[0];
    compound[b * DIM + tid] = c;
    comp[tid] = c;
  }
  __syncthreads();
  if (tid < DIM) {
    float acc = 0.f;
    for (int d = 0; d < DIM; d += 4) {
      float4 wv = *(const float4*)&Wa[tid * DIM + d];
      float4 x  = *(const float4*)&comp[d];
      acc = fmaf(x.x, wv.x, fmaf(x.y, wv.y, fmaf(x.z, wv.z, fmaf(x.w, wv.w, acc))));
    }
    hv[b * DIM + tid] = fmaxf(acc + ba[tid], 0.f);
  }
}

// ------------------------- fp8 conv epilogue helper -------------------------
template <bool ROWCHK, bool BF16OUT>
__device__ inline void conv_epi(const float4v& acc, int rc,
                                char* __restrict__ dst,
                                unsigned short* __restrict__ dstX,
                                float bias, int dstart, int lane, int cc) {
  const int lj = lane & 15;
  int orow = rc * 16 + (lane >> 4) * 4;
  int ocol = cc * 16 + lj;
  #pragma unroll
  for (int jj = 0; jj < 4; ++jj) {
    float v = fmaxf(acc[jj] + bias, 0.f);
    if constexpr (BF16OUT) {
      dstX[(orow + jj) * XRS + ocol] = f2bf(v);
    } else {
      char sv = 0;
      if (!ROWCHK || (unsigned)(dstart + orow + jj) < LPROT) {
        int p = __builtin_amdgcn_cvt_pk_fp8_f32(v, 0.f, 0, false);
        sv = (char)p;
      }
      dst[(orow + jj) * FRS + 8 + ocol] = sv;
    }
  }
}

// --------------- fp8 conv phase (Toeplitz MFMA, ILP-2 on row tiles) ---------
template <int N_RC, bool ROWCHK, bool BF16OUT>
__device__ inline void conv_fp8(const char* __restrict__ src, char* __restrict__ dst,
                                unsigned short* __restrict__ dstX,
                                const long* bfr, float bias, int dstart,
                                int lane, int cc) {
  const int lj = lane & 15, k0 = (lane >> 4) * 8;
  const int acol = 8 + cc * 16 + k0;
  #pragma unroll 1
  for (int rp = 0; rp < N_RC / 2; ++rp) {
    const int rc0 = rp * 2, rc1 = rc0 + 1;
    float4v acc0 = {0.f, 0.f, 0.f, 0.f};
    float4v acc1 = {0.f, 0.f, 0.f, 0.f};
    #pragma unroll
    for (int ki = 0; ki < KSZ; ++ki) {
      long a0 = *(const long*)(src + (rc0 * 16 + lj + ki) * FRS + acol);
      long a1 = *(const long*)(src + (rc1 * 16 + lj + ki) * FRS + acol);
      acc0 = __builtin_amdgcn_mfma_f32_16x16x32_fp8_fp8(a0, bfr[ki], acc0, 0, 0, 0);
      acc1 = __builtin_amdgcn_mfma_f32_16x16x32_fp8_fp8(a1, bfr[ki], acc1, 0, 0, 0);
    }
    conv_epi<ROWCHK, BF16OUT>(acc0, rc0, dst, dstX, bias, dstart, lane, cc);
    conv_epi<ROWCHK, BF16OUT>(acc1, rc1, dst, dstX, bias, dstart, lane, cc);
  }
  if (N_RC & 1) {
    const int rc = N_RC - 1;
    float4v acc = {0.f, 0.f, 0.f, 0.f};
    #pragma unroll
    for (int ki = 0; ki < KSZ; ++ki) {
      long a = *(const long*)(src + (rc * 16 + lj + ki) * FRS + acol);
      acc = __builtin_amdgcn_mfma_f32_16x16x32_fp8_fp8(a, bfr[ki], acc, 0, 0, 0);
    }
    conv_epi<ROWCHK, BF16OUT>(acc, rc, dst, dstX, bias, dstart, lane, cc);
  }
}

// ------------- fused protein branch (bufX overlays buf1: 38.4KB LDS) --------
__global__ __launch_bounds__(512, 8) void k_protein(const int* __restrict__ words,
                                                    const float* __restrict__ emb_word,
                                                    const long* __restrict__ wbf,
                                                    const float* __restrict__ bc,
                                                    const float* __restrict__ Wa,
                                                    const float* __restrict__ ba,
                                                    const float* __restrict__ hvec,
                                                    const float* __restrict__ pmask,
                                                    float* __restrict__ prot_part) {
  __shared__ __align__(16) char pool[38400];
  char* buf0 = pool;                                     // fp8, 106x152 (16128)
  char* buf1 = pool + 16128;                             // fp8, 96x152 (14592)
  unsigned short* bufX = (unsigned short*)(pool + 16128);// bf16 64x136, OVERLAYS buf1
  float* wpart = (float*)(pool + 33536);                 // 64x8 (2048)
  float* w_l   = (float*)(pool + 35584);                 // 64 (256)
  float* red   = (float*)(pool + 35840);                 // 4x128 (2048)
  float* h_s   = (float*)(pool + 37888);                 // 128 (512)

  const int tile = blockIdx.x, b = blockIdx.y;
  const int r0   = tile * TROWS;
  const int tid  = threadIdx.x;
  const int lane = tid & 63, wave = tid >> 6;       // 8 waves
  const int lj   = lane & 15;
  const int k0   = (lane >> 4) * 8;
  const int cc   = wave;                            // 16-col chunk per wave

  // ---- zero fp8 buffers
  {
    int4 z = {0, 0, 0, 0};
    int4* p0 = (int4*)pool;
    for (int i = tid; i < 30720 / 16; i += 512) p0[i] = z;
  }
  if (tid < DIM) h_s[tid] = hvec[b * DIM + tid];

  // ---- gather input rows r0-15 .. r0+90 as fp8 into buf0
  for (int idx = tid; idx < B0_ROWS * 32; idx += 512) {
    int rloc = idx >> 5, c4 = idx & 31;
    int rg = r0 - 15 + rloc;
    if (rg >= 0 && rg < LPROT) {
      int w = words[b * LPROT + rg];
      float4 v = ((const float4*)(emb_word + (long)w * DIM))[c4];
      int p = __builtin_amdgcn_cvt_pk_fp8_f32(v.x, v.y, 0, false);
      p = __builtin_amdgcn_cvt_pk_fp8_f32(v.z, v.w, p, true);
      *(int*)(buf0 + rloc * FRS + 8 + c4 * 4) = p;
    }
  }

  // ---- 3 conv layers (fp8 Toeplitz MFMA, precomputed weight fragments)
  #pragma unroll 1
  for (int lp = 0; lp < 3; ++lp) {
    __syncthreads();
    long bfr[KSZ];
    const long* wsrc = wbf + (lp * 64 + lane) * KSZ;
    #pragma unroll
    for (int ki = 0; ki < KSZ; ++ki) bfr[ki] = wsrc[ki];
    float bias = bc[lp];

    if (lp == 0)
      conv_fp8<6, true, false>(buf0, buf1, nullptr, bfr, bias, r0 - 10, lane, cc);
    else if (lp == 1)
      conv_fp8<5, true, false>(buf1, buf0, nullptr, bfr, bias, r0 - 5, lane, cc);
    else
      conv_fp8<4, false, true>(buf0, nullptr, bufX, bfr, bias, r0, lane, cc);
  }
  __syncthreads();

  // ---- hs = relu(X @ Wa^T + ba): X = bufX (bf16), in place
  {
    const char* xb = (const char*)bufX;
    float4v acc[4];
    #pragma unroll
    for (int rc = 0; rc < 4; ++rc) acc[rc] = (float4v){0.f, 0.f, 0.f, 0.f};
    #pragma unroll
    for (int ks = 0; ks < 4; ++ks) {
      const float* wrow = Wa + (cc * 16 + lj) * DIM + ks * 32 + k0;
      short8v bf = cvt8(wrow);
      #pragma unroll
      for (int rc = 0; rc < 4; ++rc) {
        short8v a = *(const short8v*)(xb + (rc * 16 + lj) * (XRS * 2) + (ks * 32 + k0) * 2);
        acc[rc] = __builtin_amdgcn_mfma_f32_16x16x32_bf16(a, bf, acc[rc], 0, 0, 0);
      }
    }
    __syncthreads();
    float bav = ba[cc * 16 + lj];
    #pragma unroll
    for (int rc = 0; rc < 4; ++rc) {
      int orow = rc * 16 + (lane >> 4) * 4;
      int ocol = cc * 16 + lj;
      #pragma unroll
      for (int jj = 0; jj < 4; ++jj) {
        float v = fmaxf(acc[rc][jj] + bav, 0.f);
        bufX[(orow + jj) * XRS + ocol] = f2bf(v);
      }
    }
  }
  __syncthreads();

  // ---- attention weights: w_l = tanh(hs[l]·h) * pmask  (vectorized reads)
  {
    int l = tid >> 3, part = tid & 7, d0 = part * 16;
    short8v v0 = *(const short8v*)&bufX[l * XRS + d0];
    short8v v1 = *(const short8v*)&bufX[l * XRS + d0 + 8];
    float4 h0 = *(const float4*)&h_s[d0];
    float4 h1 = *(const float4*)&h_s[d0 + 4];
    float4 h2 = *(const float4*)&h_s[d0 + 8];
    float4 h3 = *(const float4*)&h_s[d0 + 12];
    float s = 0.f;
    s = fmaf(bf2f((unsigned short)v0[0]), h0.x, s);
    s = fmaf(bf2f((unsigned short)v0[1]), h0.y, s);
    s = fmaf(bf2f((unsigned short)v0[2]), h0.z, s);
    s = fmaf(bf2f((unsigned short)v0[3]), h0.w, s);
    s = fmaf(bf2f((unsigned short)v0[4]), h1.x, s);
    s = fmaf(bf2f((unsigned short)v0[5]), h1.y, s);
    s = fmaf(bf2f((unsigned short)v0[6]), h1.z, s);
    s = fmaf(bf2f((unsigned short)v0[7]), h1.w, s);
    s = fmaf(bf2f((unsigned short)v1[0]), h2.x, s);
    s = fmaf(bf2f((unsigned short)v1[1]), h2.y, s);
    s = fmaf(bf2f((unsigned short)v1[2]), h2.z, s);
    s = fmaf(bf2f((unsigned short)v1[3]), h2.w, s);
    s = fmaf(bf2f((unsigned short)v1[4]), h3.x, s);
    s = fmaf(bf2f((unsigned short)v1[5]), h3.y, s);
    s = fmaf(bf2f((unsigned short)v1[6]), h3.z, s);
    s = fmaf(bf2f((unsigned short)v1[7]), h3.w, s);
    wpart[l * 8 + part] = s;
  }
  __syncthreads();
  if (tid < TROWS) {
    float s = 0.f;
    #pragma unroll
    for (int p = 0; p < 8; ++p) s += wpart[tid * 8 + p];
    w_l[tid] = tanhf(s) * pmask[b * LPROT + r0 + tid];
  }
  __syncthreads();

  // ---- partial protein numerator
  {
    int e = tid & 127, g = tid >> 7;
    float s = 0.f;
    #pragma unroll
    for (int j = 0; j < 16; ++j) {
      int l = g * 16 + j;
      s = fmaf(w_l[l], bf2f(bufX[l * XRS + e]), s);
    }
    red[g * DIM + e] = s;
  }
  __syncthreads();
  if (tid < DIM)
    prot_part[((long)b * NTILES + tile) * DIM + tid] =
        red[tid] + red[DIM + tid] + red[2 * DIM + tid] + red[3 * DIM + tid];
}

// ------------------------------------------------ head MLP + affinity per b
__global__ __launch_bounds__(256) void k_head(const float* __restrict__ prot_part,
                                              const float* __restrict__ pmask,
                                              const float* __restrict__ compound,
                                              const float* __restrict__ Wo,
                                              const float* __restrict__ bo,
                                              const float* __restrict__ Wi,
                                              const float* __restrict__ bi,
                                              float* __restrict__ out) {
  int b = blockIdx.x, tid = threadIdx.x;
  __shared__ float cat[2 * DIM];
  __shared__ float redl[256];

  float ps = 0.f;
  for (int l = tid; l < LPROT; l += 256) ps += pmask[b * LPROT + l];
  redl[tid] = ps; __syncthreads();
  for (int st = 128; st > 0; st >>= 1) {
    if (tid < st) redl[tid] += redl[tid + st];
    __syncthreads();
  }
  float pden = redl[0];
  __syncthreads();

  if (tid < DIM) {
    cat[tid] = compound[b * DIM + tid];
    float s = 0.f;
    for (int t = 0; t < NTILES; ++t) s += prot_part[(b * NTILES + t) * DIM + tid];
    cat[DIM + tid] = s / pden;
  }
  __syncthreads();

  for (int j = 0; j < 2; ++j) {
    const float* W = Wo + j * 2 * DIM * 2 * DIM + tid * 2 * DIM;
    float acc = 0.f;
    for (int d = 0; d < 2 * DIM; d += 4) {
      float4 c = *(const float4*)&cat[d];
      float4 w = *(const float4*)&W[d];
      acc = fmaf(c.x, w.x, fmaf(c.y, w.y, fmaf(c.z, w.z, fmaf(c.w, w.w, acc))));
    }
    float v = fmaxf(acc + bo[j * 2 * DIM + tid], 0.f);
    __syncthreads();
    cat[tid] = v;
    __syncthreads();
  }

  float p = cat[tid] * Wi[tid];
  redl[tid] = p; __syncthreads();
  for (int st = 128; st > 0; st >>= 1) {
    if (tid < st) redl[tid] += redl[tid + st];
    __syncthreads();
  }
  if (tid == 0) out[1 + b] = redl[0] + bi[0];
}

// ----------------------------------------------------------------- MSE loss
__global__ void k_loss(const float* __restrict__ label, float* __restrict__ out) {
  int t = threadIdx.x;
  float d = out[1 + t] - label[t];
  float v = d * d;
  #pragma unroll
  for (int s = 32; s > 0; s >>= 1) v += __shfl_down(v, s);
  if (t == 0) out[0] = v * (1.f / 64.f);
}

extern "C" void kernel_launch(void* const* d_in, const int* in_sizes, int n_in,
                              void* d_out, int out_size, void* d_ws, size_t ws_size,
                              hipStream_t stream) {
  const int*   fingerprints = (const int*)d_in[0];
  const float* adjacency    = (const float*)d_in[1];
  const int*   words        = (const int*)d_in[2];
  const float* cmask        = (const float*)d_in[3];
  const float* pmask        = (const float*)d_in[4];
  const float* label        = (const float*)d_in[5];
  const float* emb_fp       = (const float*)d_in[6];
  const float* emb_word     = (const float*)d_in[7];
  const float* Wg           = (const float*)d_in[8];
  const float* bg           = (const float*)d_in[9];
  const float* Wc           = (const float*)d_in[10];
  const float* bc           = (const float*)d_in[11];
  const float* Wa           = (const float*)d_in[12];
  const float* ba           = (const float*)d_in[13];
  const float* Wo           = (const float*)d_in[14];
  const float* bo           = (const float*)d_in[15];
  const float* Wi           = (const float*)d_in[16];
  const float* bi           = (const float*)d_in[17];
  float* out = (float*)d_out;

  unsigned short* Abf = (unsigned short*)d_ws;                 // 8.39 MB
  float* compound  = (float*)(Abf + (long)NB * NA * NA);
  float* hv        = compound + NB * DIM;
  float* prot_part = hv + NB * DIM;                            // 64*32*128
  long*  wbf       = (long*)(prot_part + NB * NTILES * DIM);   // 3*64*11

  k_pre<<<2049, 256, 0, stream>>>(adjacency, Abf, Wc, wbf);
  k_gnn<<<NB, 512, 0, stream>>>(fingerprints, emb_fp, Abf, Wg, bg,
                                cmask, Wa, ba, compound, hv);
  k_protein<<<dim3(NTILES, NB), 512, 0, stream>>>(words, emb_word, wbf, bc, Wa, ba,
                                                  hv, pmask, prot_part);
  k_head<<<NB, 256, 0, stream>>>(prot_part, pmask, compound, Wo, bo, Wi, bi, out);
  k_loss<<<1, 64, 0, stream>>>(label, out);
}